// Round 1
// baseline (557.435 us; speedup 1.0000x reference)
//
#include <hip/hip_runtime.h>

typedef __bf16 bf16;
typedef __bf16 bf16x8 __attribute__((ext_vector_type(8)));
typedef float f32x4 __attribute__((ext_vector_type(4)));

#define DEV __device__ __forceinline__

// async global->LDS, 16B per lane. LDS dest must be wave-uniform base + lane*16.
DEV void gload16(const void* g, void* l) {
  __builtin_amdgcn_global_load_lds(
      (__attribute__((address_space(1))) void*)g,
      (__attribute__((address_space(3))) void*)l,
      16, 0, 0);
}

// ---------------------------------------------------------------- fp32 -> bf16
__global__ __launch_bounds__(256) void cvt_f32_to_bf16(
    const float* __restrict__ in, bf16* __restrict__ out, long n) {
  long i = ((long)blockIdx.x * 256 + threadIdx.x) * 8;
  if (i + 8 > n) return;
  const float4* p = (const float4*)(in + i);
  float4 a = p[0], b = p[1];
  bf16x8 o;
  o[0] = (bf16)a.x; o[1] = (bf16)a.y; o[2] = (bf16)a.z; o[3] = (bf16)a.w;
  o[4] = (bf16)b.x; o[5] = (bf16)b.y; o[6] = (bf16)b.z; o[7] = (bf16)b.w;
  *(bf16x8*)(out + i) = o;
}

// ---------------------------------------------------------------- GEMM  C = A * B^T
// A: [M][K] bf16 row-major, B: [N][K] bf16 row-major, C: [M][N] OutT.
// 128x128 tile, BK=64, 4 waves (2x2), each wave 64x64 = 4x4 frags of 16x16x32.
template <typename OutT>
__global__ __launch_bounds__(256) void gemm_bt(
    const bf16* __restrict__ A, const bf16* __restrict__ B, OutT* __restrict__ C,
    int M, int N, int K) {
  __shared__ bf16 As[128 * 64];
  __shared__ bf16 Bs[128 * 64];
  const int tid = threadIdx.x;
  const int lane = tid & 63;
  const int wv = tid >> 6;
  const int wm = wv >> 1, wn = wv & 1;
  const int l15 = lane & 15, l4 = lane >> 4;
  const long m0 = (long)blockIdx.y * 128;
  const long n0 = (long)blockIdx.x * 128;

  f32x4 acc[4][4];
#pragma unroll
  for (int i = 0; i < 4; ++i)
#pragma unroll
    for (int j = 0; j < 4; ++j) acc[i][j] = (f32x4){0.f, 0.f, 0.f, 0.f};

  for (int k0 = 0; k0 < K; k0 += 64) {
#pragma unroll
    for (int it = 0; it < 4; ++it) {
      const int flat = it * 256 + tid;   // 0..1023
      const int row = flat >> 3;
      const int col = (flat & 7) * 8;
      gload16(A + (m0 + row) * (long)K + k0 + col, &As[flat * 8]);
      gload16(B + (n0 + row) * (long)K + k0 + col, &Bs[flat * 8]);
    }
    __syncthreads();
#pragma unroll
    for (int kk = 0; kk < 2; ++kk) {
      bf16x8 af[4], bfr[4];
#pragma unroll
      for (int i = 0; i < 4; ++i)
        af[i] = *(const bf16x8*)&As[(wm * 64 + i * 16 + l15) * 64 + kk * 32 + l4 * 8];
#pragma unroll
      for (int j = 0; j < 4; ++j)
        bfr[j] = *(const bf16x8*)&Bs[(wn * 64 + j * 16 + l15) * 64 + kk * 32 + l4 * 8];
#pragma unroll
      for (int i = 0; i < 4; ++i)
#pragma unroll
        for (int j = 0; j < 4; ++j)
          acc[i][j] = __builtin_amdgcn_mfma_f32_16x16x32_bf16(af[i], bfr[j], acc[i][j], 0, 0, 0);
    }
    __syncthreads();
  }

#pragma unroll
  for (int i = 0; i < 4; ++i)
#pragma unroll
    for (int j = 0; j < 4; ++j) {
      const long row = m0 + wm * 64 + i * 16 + l4 * 4;
      const long col = n0 + wn * 64 + j * 16 + l15;
#pragma unroll
      for (int r = 0; r < 4; ++r)
        C[(row + r) * (long)N + col] = (OutT)acc[i][j][r];
    }
}

// ---------------------------------------------------------------- RMSNorm + RoPE for Q,K
// qkv: [4096][3072] bf16 (q 0..2047 | k 2048..2559 | v 2560..3071)
// Qh: [B][32][T][64] bf16, Kh: [B][8][T][64] bf16. One wave per (row, head).
__global__ __launch_bounds__(256) void qk_norm_rope(
    const bf16* __restrict__ qkv, const float* __restrict__ qw,
    const float* __restrict__ kw, bf16* __restrict__ Qh, bf16* __restrict__ Kh) {
  const int wg = blockIdx.x * 4 + (threadIdx.x >> 6);   // 0 .. 4096*40-1
  const int lane = threadIdx.x & 63;
  const int row = wg / 40;
  const int head = wg - row * 40;                       // 0..31 q, 32..39 k
  const int b = row >> 11, t = row & 2047;
  const bool is_q = head < 32;
  const int col0 = is_q ? head * 64 : 2048 + (head - 32) * 64;

  float v = (float)qkv[(long)row * 3072 + col0 + lane];
  float ss = v * v;
  ss += __shfl_xor(ss, 1);
  ss += __shfl_xor(ss, 2);
  ss += __shfl_xor(ss, 4);
  ss += __shfl_xor(ss, 8);
  ss += __shfl_xor(ss, 16);
  ss += __shfl_xor(ss, 32);
  const float norm = rsqrtf(ss * (1.0f / 64.0f) + 1e-6f);
  const float* wn = is_q ? qw : kw;
  float xn = v * norm * wn[lane];

  // RoPE: inv_freq[i] = theta^(-i/32), i = lane&31; rotate-half pairing (d, d+32)
  const int fi = lane & 31;
  const float inv_freq = expf(-(float)fi * (9.210340371976184f / 32.0f)); // ln(1e4)
  const float fr = (float)t * inv_freq;
  float sn, cs;
  sincosf(fr, &sn, &cs);
  const float xo = __shfl_xor(xn, 32);
  const float xr = (lane < 32) ? -xo : xo;
  const float res = xn * cs + xr * sn;

  if (is_q)
    Qh[(((long)b * 32 + head) * 2048 + t) * 64 + lane] = (bf16)res;
  else
    Kh[(((long)b * 8 + (head - 32)) * 2048 + t) * 64 + lane] = (bf16)res;
}

// ---------------------------------------------------------------- V transpose
// qkv v-cols -> Vt [B*8][64 d][2048 t] bf16 (so PV B-operand reads contiguous kv)
__global__ __launch_bounds__(256) void v_transpose(
    const bf16* __restrict__ qkv, bf16* __restrict__ Vt) {
  const int bh = blockIdx.x;          // b*8 + kh
  const int t0 = blockIdx.y * 64;
  const int b = bh >> 3, kh = bh & 7;
  __shared__ bf16 tile[64][72];       // +8 pad
  const int tid = threadIdx.x;
#pragma unroll
  for (int it = 0; it < 2; ++it) {
    const int tt = it * 32 + (tid >> 3);
    const int d0 = (tid & 7) * 8;
    bf16x8 val = *(const bf16x8*)&qkv[((long)b * 2048 + t0 + tt) * 3072 + 2560 + kh * 64 + d0];
#pragma unroll
    for (int j = 0; j < 8; ++j) tile[tt][d0 + j] = val[j];
  }
  __syncthreads();
#pragma unroll
  for (int it = 0; it < 2; ++it) {
    const int d = it * 32 + (tid >> 3);
    const int tb = (tid & 7) * 8;
    bf16x8 o;
#pragma unroll
    for (int j = 0; j < 8; ++j) o[j] = tile[tb + j][d];
    *(bf16x8*)&Vt[((long)bh * 64 + d) * 2048 + t0 + tb] = o;
  }
}

// ---------------------------------------------------------------- causal flash attention
// Q: [B][32][T][64], K: [B][8][T][64], Vt: [B][8][64][T], O: [B*T][2048] (col = h*64+d)
// Block: 4 waves x 32 q-rows = 128 q-rows; KV tiles of 64.
__global__ __launch_bounds__(256) void attn_fwd(
    const bf16* __restrict__ Q, const bf16* __restrict__ K,
    const bf16* __restrict__ Vt, bf16* __restrict__ O) {
  const int b = blockIdx.z, h = blockIdx.y, q0 = blockIdx.x * 128;
  const int kvh = h >> 2;
  const bf16* Qp = Q + (((long)b * 32 + h) * 2048 + q0) * 64;
  const bf16* Kp = K + ((long)b * 8 + kvh) * (2048L * 64);
  const bf16* Vp = Vt + ((long)b * 8 + kvh) * (64L * 2048);

  __shared__ bf16 Ks[64 * 64];
  __shared__ bf16 Vs[64 * 64];
  __shared__ bf16 Ps[4][32 * 64];

  const int tid = threadIdx.x, lane = tid & 63, w = tid >> 6;
  const int l15 = lane & 15, l4 = lane >> 4;
  const int qwr = q0 + w * 32;            // wave's base q row

  bf16x8 qf[2][2];
#pragma unroll
  for (int m = 0; m < 2; ++m)
#pragma unroll
    for (int kk = 0; kk < 2; ++kk)
      qf[m][kk] = *(const bf16x8*)(Qp + (w * 32 + m * 16 + l15) * 64 + kk * 32 + l4 * 8);

  f32x4 accO[2][4];
  float Mr[2][4], Lr[2][4];
#pragma unroll
  for (int m = 0; m < 2; ++m)
#pragma unroll
    for (int j = 0; j < 4; ++j) {
      accO[m][j] = (f32x4){0.f, 0.f, 0.f, 0.f};
      Mr[m][j] = -1e30f;
      Lr[m][j] = 0.f;
    }

  const float scale = 0.125f;
  const int ktiles = (q0 >> 6) + 2;       // k0 < q0+128
  for (int kt = 0; kt < ktiles; ++kt) {
    const int k0 = kt * 64;
#pragma unroll
    for (int it = 0; it < 2; ++it) {
      const int f2 = it * 256 + tid;      // 0..511
      const int row = f2 >> 3;
      const int c8 = (f2 & 7) * 8;
      gload16(Kp + (long)(k0 + row) * 64 + c8, &Ks[f2 * 8]);
      gload16(Vp + (long)row * 2048 + k0 + c8, &Vs[f2 * 8]);
    }
    __syncthreads();

    if (k0 <= qwr + 31) {                 // wave has unmasked elements
      f32x4 s[2][4];
#pragma unroll
      for (int m = 0; m < 2; ++m)
#pragma unroll
        for (int n = 0; n < 4; ++n) s[m][n] = (f32x4){0.f, 0.f, 0.f, 0.f};
#pragma unroll
      for (int kk = 0; kk < 2; ++kk) {
        bf16x8 kf[4];
#pragma unroll
        for (int n = 0; n < 4; ++n)
          kf[n] = *(const bf16x8*)&Ks[(n * 16 + l15) * 64 + kk * 32 + l4 * 8];
#pragma unroll
        for (int m = 0; m < 2; ++m)
#pragma unroll
          for (int n = 0; n < 4; ++n)
            s[m][n] = __builtin_amdgcn_mfma_f32_16x16x32_bf16(qf[m][kk], kf[n], s[m][n], 0, 0, 0);
      }
      const bool edge = (k0 + 63 > qwr);
#pragma unroll
      for (int m = 0; m < 2; ++m)
#pragma unroll
        for (int n = 0; n < 4; ++n)
#pragma unroll
          for (int r = 0; r < 4; ++r) {
            float v = s[m][n][r] * scale;
            if (edge) {
              const int qrow = qwr + m * 16 + l4 * 4 + r;
              const int kcol = k0 + n * 16 + l15;
              if (kcol > qrow) v = -1e30f;
            }
            s[m][n][r] = v;
          }
      // online softmax per (m,r); row elements live in 16-lane groups (l15) x 4 n-tiles
#pragma unroll
      for (int m = 0; m < 2; ++m)
#pragma unroll
        for (int r = 0; r < 4; ++r) {
          float pm = fmaxf(fmaxf(s[m][0][r], s[m][1][r]), fmaxf(s[m][2][r], s[m][3][r]));
          pm = fmaxf(pm, __shfl_xor(pm, 1));
          pm = fmaxf(pm, __shfl_xor(pm, 2));
          pm = fmaxf(pm, __shfl_xor(pm, 4));
          pm = fmaxf(pm, __shfl_xor(pm, 8));
          const float newM = fmaxf(Mr[m][r], pm);
          const float sc = __expf(Mr[m][r] - newM);
          Mr[m][r] = newM;
          float rs = 0.f;
#pragma unroll
          for (int n = 0; n < 4; ++n) {
            const float pv = __expf(s[m][n][r] - newM);
            s[m][n][r] = pv;
            rs += pv;
          }
          rs += __shfl_xor(rs, 1);
          rs += __shfl_xor(rs, 2);
          rs += __shfl_xor(rs, 4);
          rs += __shfl_xor(rs, 8);
          Lr[m][r] = Lr[m][r] * sc + rs;
#pragma unroll
          for (int dn = 0; dn < 4; ++dn) accO[m][dn][r] *= sc;
        }
      // P (D-layout) -> LDS -> A-frag layout for PV
#pragma unroll
      for (int m = 0; m < 2; ++m)
#pragma unroll
        for (int n = 0; n < 4; ++n)
#pragma unroll
          for (int r = 0; r < 4; ++r)
            Ps[w][(m * 16 + l4 * 4 + r) * 64 + n * 16 + l15] = (bf16)s[m][n][r];
#pragma unroll
      for (int kk = 0; kk < 2; ++kk) {
        bf16x8 pf[2], vf[4];
#pragma unroll
        for (int m = 0; m < 2; ++m)
          pf[m] = *(const bf16x8*)&Ps[w][(m * 16 + l15) * 64 + kk * 32 + l4 * 8];
#pragma unroll
        for (int dn = 0; dn < 4; ++dn)
          vf[dn] = *(const bf16x8*)&Vs[(dn * 16 + l15) * 64 + kk * 32 + l4 * 8];
#pragma unroll
        for (int m = 0; m < 2; ++m)
#pragma unroll
          for (int dn = 0; dn < 4; ++dn)
            accO[m][dn] = __builtin_amdgcn_mfma_f32_16x16x32_bf16(pf[m], vf[dn], accO[m][dn], 0, 0, 0);
      }
    }
    __syncthreads();
  }

#pragma unroll
  for (int m = 0; m < 2; ++m)
#pragma unroll
    for (int r = 0; r < 4; ++r) {
      const float inv = 1.0f / Lr[m][r];
      const long qrow = q0 + w * 32 + m * 16 + l4 * 4 + r;
      const long base = ((long)b * 2048 + qrow) * 2048 + h * 64;
#pragma unroll
      for (int dn = 0; dn < 4; ++dn)
        O[base + dn * 16 + l15] = (bf16)(accO[m][dn][r] * inv);
    }
}

// ----------------------------------------------------------------
extern "C" void kernel_launch(void* const* d_in, const int* in_sizes, int n_in,
                              void* d_out, int out_size, void* d_ws, size_t ws_size,
                              hipStream_t stream) {
  const float* x   = (const float*)d_in[0];
  const float* wq  = (const float*)d_in[1];
  const float* wk  = (const float*)d_in[2];
  const float* wv  = (const float*)d_in[3];
  const float* wo  = (const float*)d_in[4];
  const float* qnw = (const float*)d_in[5];
  const float* knw = (const float*)d_in[6];
  float* out = (float*)d_out;

  char* ws = (char*)d_ws;
  size_t off = 0;
  auto carve = [&](size_t bytes) -> void* {
    void* p = ws + off;
    off += (bytes + 255) & ~(size_t)255;
    return p;
  };
  bf16* xb    = (bf16*)carve(8388608ull * 2);    // x bf16 [4096][2048]; reused as attn_out
  bf16* wqkvb = (bf16*)carve(6291456ull * 2);    // [3072][2048]
  bf16* wob   = (bf16*)carve(4194304ull * 2);    // [2048][2048]
  bf16* qkvb  = (bf16*)carve(12582912ull * 2);   // [4096][3072]
  bf16* Qh    = (bf16*)carve(8388608ull * 2);    // [2][32][2048][64]
  bf16* Kh    = (bf16*)carve(2097152ull * 2);    // [2][8][2048][64]
  bf16* Vt    = (bf16*)carve(2097152ull * 2);    // [2][8][64][2048]

  cvt_f32_to_bf16<<<4096, 256, 0, stream>>>(x, xb, 8388608L);
  cvt_f32_to_bf16<<<2048, 256, 0, stream>>>(wq, wqkvb, 4194304L);
  cvt_f32_to_bf16<<<512, 256, 0, stream>>>(wk, wqkvb + 4194304, 1048576L);
  cvt_f32_to_bf16<<<512, 256, 0, stream>>>(wv, wqkvb + 5242880, 1048576L);
  cvt_f32_to_bf16<<<2048, 256, 0, stream>>>(wo, wob, 4194304L);

  gemm_bt<bf16><<<dim3(24, 32), 256, 0, stream>>>(xb, wqkvb, qkvb, 4096, 3072, 2048);
  qk_norm_rope<<<40960, 256, 0, stream>>>(qkvb, qnw, knw, Qh, Kh);
  v_transpose<<<dim3(16, 32), 256, 0, stream>>>(qkvb, Vt);

  bf16* attnb = xb;   // xb is dead after the QKV GEMM
  attn_fwd<<<dim3(16, 32, 2), 256, 0, stream>>>(Qh, Kh, Vt, attnb);

  gemm_bt<float><<<dim3(16, 32), 256, 0, stream>>>(attnb, wob, out, 4096, 2048, 2048);
}

// Round 2
// 376.166 us; speedup vs baseline: 1.4819x; 1.4819x over previous
//
#include <hip/hip_runtime.h>

typedef __bf16 bf16;
typedef __bf16 bf16x8 __attribute__((ext_vector_type(8)));
typedef float f32x4 __attribute__((ext_vector_type(4)));

#define DEV __device__ __forceinline__

// async global->LDS, 16B per lane. LDS dest must be wave-uniform base + lane*16.
DEV void gload16(const void* g, void* l) {
  __builtin_amdgcn_global_load_lds(
      (__attribute__((address_space(1))) void*)g,
      (__attribute__((address_space(3))) void*)l,
      16, 0, 0);
}

DEV unsigned pack_bf16(float a, float b) {
  union { bf16 h[2]; unsigned u; } u;
  u.h[0] = (bf16)a; u.h[1] = (bf16)b;
  return u.u;
}

// ---------------------------------------------------------------- fp32 -> bf16
__global__ __launch_bounds__(256) void cvt_f32_to_bf16(
    const float* __restrict__ in, bf16* __restrict__ out, long n) {
  long i = ((long)blockIdx.x * 256 + threadIdx.x) * 8;
  if (i + 8 > n) return;
  const float4* p = (const float4*)(in + i);
  float4 a = p[0], b = p[1];
  bf16x8 o;
  o[0] = (bf16)a.x; o[1] = (bf16)a.y; o[2] = (bf16)a.z; o[3] = (bf16)a.w;
  o[4] = (bf16)b.x; o[5] = (bf16)b.y; o[6] = (bf16)b.z; o[7] = (bf16)b.w;
  *(bf16x8*)(out + i) = o;
}

// ---------------------------------------------------------------- GEMM  C = A * B^T
template <typename OutT>
__global__ __launch_bounds__(256) void gemm_bt(
    const bf16* __restrict__ A, const bf16* __restrict__ B, OutT* __restrict__ C,
    int M, int N, int K) {
  __shared__ bf16 As[128 * 64];
  __shared__ bf16 Bs[128 * 64];
  const int tid = threadIdx.x;
  const int lane = tid & 63;
  const int wv = tid >> 6;
  const int wm = wv >> 1, wn = wv & 1;
  const int l15 = lane & 15, l4 = lane >> 4;
  const long m0 = (long)blockIdx.y * 128;
  const long n0 = (long)blockIdx.x * 128;

  f32x4 acc[4][4];
#pragma unroll
  for (int i = 0; i < 4; ++i)
#pragma unroll
    for (int j = 0; j < 4; ++j) acc[i][j] = (f32x4){0.f, 0.f, 0.f, 0.f};

  for (int k0 = 0; k0 < K; k0 += 64) {
#pragma unroll
    for (int it = 0; it < 4; ++it) {
      const int flat = it * 256 + tid;   // 0..1023
      const int row = flat >> 3;
      const int col = (flat & 7) * 8;
      gload16(A + (m0 + row) * (long)K + k0 + col, &As[flat * 8]);
      gload16(B + (n0 + row) * (long)K + k0 + col, &Bs[flat * 8]);
    }
    __syncthreads();
#pragma unroll
    for (int kk = 0; kk < 2; ++kk) {
      bf16x8 af[4], bfr[4];
#pragma unroll
      for (int i = 0; i < 4; ++i)
        af[i] = *(const bf16x8*)&As[(wm * 64 + i * 16 + l15) * 64 + kk * 32 + l4 * 8];
#pragma unroll
      for (int j = 0; j < 4; ++j)
        bfr[j] = *(const bf16x8*)&Bs[(wn * 64 + j * 16 + l15) * 64 + kk * 32 + l4 * 8];
#pragma unroll
      for (int i = 0; i < 4; ++i)
#pragma unroll
        for (int j = 0; j < 4; ++j)
          acc[i][j] = __builtin_amdgcn_mfma_f32_16x16x32_bf16(af[i], bfr[j], acc[i][j], 0, 0, 0);
    }
    __syncthreads();
  }

#pragma unroll
  for (int i = 0; i < 4; ++i)
#pragma unroll
    for (int j = 0; j < 4; ++j) {
      const long row = m0 + wm * 64 + i * 16 + l4 * 4;
      const long col = n0 + wn * 64 + j * 16 + l15;
#pragma unroll
      for (int r = 0; r < 4; ++r)
        C[(row + r) * (long)N + col] = (OutT)acc[i][j][r];
    }
}

// ---------------------------------------------------------------- RMSNorm + RoPE for Q,K
__global__ __launch_bounds__(256) void qk_norm_rope(
    const bf16* __restrict__ qkv, const float* __restrict__ qw,
    const float* __restrict__ kw, bf16* __restrict__ Qh, bf16* __restrict__ Kh) {
  const int wg = blockIdx.x * 4 + (threadIdx.x >> 6);   // 0 .. 4096*40-1
  const int lane = threadIdx.x & 63;
  const int row = wg / 40;
  const int head = wg - row * 40;                       // 0..31 q, 32..39 k
  const int b = row >> 11, t = row & 2047;
  const bool is_q = head < 32;
  const int col0 = is_q ? head * 64 : 2048 + (head - 32) * 64;

  float v = (float)qkv[(long)row * 3072 + col0 + lane];
  float ss = v * v;
  ss += __shfl_xor(ss, 1);
  ss += __shfl_xor(ss, 2);
  ss += __shfl_xor(ss, 4);
  ss += __shfl_xor(ss, 8);
  ss += __shfl_xor(ss, 16);
  ss += __shfl_xor(ss, 32);
  const float norm = rsqrtf(ss * (1.0f / 64.0f) + 1e-6f);
  const float* wn = is_q ? qw : kw;
  float xn = v * norm * wn[lane];

  const int fi = lane & 31;
  const float inv_freq = expf(-(float)fi * (9.210340371976184f / 32.0f)); // ln(1e4)
  const float fr = (float)t * inv_freq;
  float sn, cs;
  sincosf(fr, &sn, &cs);
  const float xo = __shfl_xor(xn, 32);
  const float xr = (lane < 32) ? -xo : xo;
  const float res = xn * cs + xr * sn;

  if (is_q)
    Qh[(((long)b * 32 + head) * 2048 + t) * 64 + lane] = (bf16)res;
  else
    Kh[(((long)b * 8 + (head - 32)) * 2048 + t) * 64 + lane] = (bf16)res;
}

// ---------------------------------------------------------------- V transpose
__global__ __launch_bounds__(256) void v_transpose(
    const bf16* __restrict__ qkv, bf16* __restrict__ Vt) {
  const int bh = blockIdx.x;          // b*8 + kh
  const int t0 = blockIdx.y * 64;
  const int b = bh >> 3, kh = bh & 7;
  __shared__ bf16 tile[64][72];       // +8 pad
  const int tid = threadIdx.x;
#pragma unroll
  for (int it = 0; it < 2; ++it) {
    const int tt = it * 32 + (tid >> 3);
    const int d0 = (tid & 7) * 8;
    bf16x8 val = *(const bf16x8*)&qkv[((long)b * 2048 + t0 + tt) * 3072 + 2560 + kh * 64 + d0];
#pragma unroll
    for (int j = 0; j < 8; ++j) tile[tt][d0 + j] = val[j];
  }
  __syncthreads();
#pragma unroll
  for (int it = 0; it < 2; ++it) {
    const int d = it * 32 + (tid >> 3);
    const int tb = (tid & 7) * 8;
    bf16x8 o;
#pragma unroll
    for (int j = 0; j < 8; ++j) o[j] = tile[tb + j][d];
    *(bf16x8*)&Vt[((long)bh * 64 + d) * 2048 + t0 + tb] = o;
  }
}

// ---------------------------------------------------------------- causal flash attention
// Swapped-operand structure: S^T = K·Q^T (lane owns q-col = l15, k in regs),
// in-register softmax (2 shuffles), P^T assembled via shfl (no P LDS),
// O^T = V^T·P^T.  K/V LDS tiles XOR-chunk-swizzled (T2, both-sides rule #21).
// Grid: x = b*32+h (64), y -> qb = 31-y (LPT: longest q-blocks first).
// Block: 4 waves x 16 q-rows = 64 q-rows; KV tiles of 64.
__global__ __launch_bounds__(256, 4) void attn_fwd(
    const bf16* __restrict__ Q, const bf16* __restrict__ K,
    const bf16* __restrict__ Vt, bf16* __restrict__ O) {
  const int b = blockIdx.x >> 5, h = blockIdx.x & 31;
  const int qb = 31 - (int)blockIdx.y;       // longest first
  const int q0 = qb * 64;
  const int kvh = h >> 2;
  const bf16* Qp = Q + (((long)b * 32 + h) * 2048 + q0) * 64;
  const bf16* Kp = K + ((long)b * 8 + kvh) * (2048L * 64);
  const bf16* Vp = Vt + ((long)b * 8 + kvh) * (64L * 2048);

  __shared__ bf16 Ks[64 * 64];   // [k][d], chunk-swizzled
  __shared__ bf16 Vs[64 * 64];   // [d][k], chunk-swizzled

  const int tid = threadIdx.x, lane = tid & 63, w = tid >> 6;
  const int l15 = lane & 15, l4 = lane >> 4;
  const int qwr = q0 + w * 16;               // wave's base q row
  const int q_g = qwr + l15;                 // this lane's q column

  // Q as B-operand (Q^T): lane holds Q[q_g][kk*32 + l4*8 + j] — hoisted
  bf16x8 qf[2];
#pragma unroll
  for (int kk = 0; kk < 2; ++kk)
    qf[kk] = *(const bf16x8*)(Qp + (w * 16 + l15) * 64 + kk * 32 + l4 * 8);

  f32x4 accO[4];                             // O^T: d = dn*16 + l4*4 + r, q = l15
#pragma unroll
  for (int dn = 0; dn < 4; ++dn) accO[dn] = (f32x4){0.f, 0.f, 0.f, 0.f};
  float M = -1e30f, L = 0.f;

  const float scale = 0.125f;
  const int swz = (l15 & 7) << 3;            // read-side XOR (bf16 units)

  for (int kt = 0; kt <= qb; ++kt) {
    const int k0 = kt * 64;
    // stage K (row=k, 64x64) and V^T (row=d, 64x64), source pre-swizzled
#pragma unroll
    for (int it = 0; it < 2; ++it) {
      const int c = it * 256 + tid;          // chunk 0..511 (16B each)
      const int row = c >> 3, cc = c & 7;
      const int scol = ((cc ^ (row & 7)) << 3);
      gload16(Kp + (long)(k0 + row) * 64 + scol, &Ks[c * 8]);
      gload16(Vp + (long)row * 2048 + k0 + scol, &Vs[c * 8]);
    }
    __syncthreads();

    // ---- S^T = K·Q^T : sT[n][r] = S[k0 + n*16 + l4*4 + r][q_g]
    f32x4 sT[4];
#pragma unroll
    for (int n = 0; n < 4; ++n) sT[n] = (f32x4){0.f, 0.f, 0.f, 0.f};
#pragma unroll
    for (int kk = 0; kk < 2; ++kk) {
      bf16x8 kf[4];
#pragma unroll
      for (int n = 0; n < 4; ++n)
        kf[n] = *(const bf16x8*)&Ks[(n * 16 + l15) * 64 + (((kk * 4 + l4) << 3) ^ swz)];
#pragma unroll
      for (int n = 0; n < 4; ++n)
        sT[n] = __builtin_amdgcn_mfma_f32_16x16x32_bf16(kf[n], qf[kk], sT[n], 0, 0, 0);
    }

    // ---- scale + causal mask (diagonal tile only)
    const bool edge = (kt == qb);
#pragma unroll
    for (int n = 0; n < 4; ++n) {
      const int kbase = k0 + n * 16 + l4 * 4;
#pragma unroll
      for (int r = 0; r < 4; ++r) {
        float v = sT[n][r] * scale;
        if (edge && (kbase + r > q_g)) v = -1e30f;
        sT[n][r] = v;
      }
    }

    // ---- online softmax over k (column q_g): per-lane 16 vals + xor16/xor32
    float pm = -1e30f;
#pragma unroll
    for (int n = 0; n < 4; ++n)
#pragma unroll
      for (int r = 0; r < 4; ++r) pm = fmaxf(pm, sT[n][r]);
    pm = fmaxf(pm, __shfl_xor(pm, 16));
    pm = fmaxf(pm, __shfl_xor(pm, 32));
    const float newM = fmaxf(M, pm);
    const float sc = __expf(M - newM);
    M = newM;
    float rs = 0.f;
#pragma unroll
    for (int n = 0; n < 4; ++n)
#pragma unroll
      for (int r = 0; r < 4; ++r) {
        const float pv = __expf(sT[n][r] - newM);
        sT[n][r] = pv;
        rs += pv;
      }
    rs += __shfl_xor(rs, 16);
    rs += __shfl_xor(rs, 32);
    L = L * sc + rs;
#pragma unroll
    for (int dn = 0; dn < 4; ++dn) accO[dn] *= sc;

    // ---- pack P^T to bf16 pairs: lo[n]=(r0,r1), hi[n]=(r2,r3) at k=n*16+l4*4
    unsigned lo[4], hi[4];
#pragma unroll
    for (int n = 0; n < 4; ++n) {
      lo[n] = pack_bf16(sT[n][0], sT[n][1]);
      hi[n] = pack_bf16(sT[n][2], sT[n][3]);
    }

    // ---- PV: O^T += V^T · P^T  (B-frag of P^T assembled via shfl)
    const int srcA = l15 | ((l4 & 1) << 5);
    const int srcB = srcA + 16;
    const bool selHi = (l4 >> 1);
#pragma unroll
    for (int kk = 0; kk < 2; ++kk) {
      unsigned d0a = __shfl(lo[2 * kk], srcA), d0b = __shfl(lo[2 * kk + 1], srcA);
      unsigned d1a = __shfl(hi[2 * kk], srcA), d1b = __shfl(hi[2 * kk + 1], srcA);
      unsigned d2a = __shfl(lo[2 * kk], srcB), d2b = __shfl(lo[2 * kk + 1], srcB);
      unsigned d3a = __shfl(hi[2 * kk], srcB), d3b = __shfl(hi[2 * kk + 1], srcB);
      union { unsigned d[4]; bf16x8 v; } pu;
      pu.d[0] = selHi ? d0b : d0a;
      pu.d[1] = selHi ? d1b : d1a;
      pu.d[2] = selHi ? d2b : d2a;
      pu.d[3] = selHi ? d3b : d3a;
      bf16x8 vf[4];
#pragma unroll
      for (int dn = 0; dn < 4; ++dn)
        vf[dn] = *(const bf16x8*)&Vs[(dn * 16 + l15) * 64 + (((kk * 4 + l4) << 3) ^ swz)];
#pragma unroll
      for (int dn = 0; dn < 4; ++dn)
        accO[dn] = __builtin_amdgcn_mfma_f32_16x16x32_bf16(vf[dn], pu.v, accO[dn], 0, 0, 0);
    }
    __syncthreads();
  }

  // ---- epilogue: O[q_g][h*64 + d] = accO^T / L   (pack bf16 pairs, u32 stores)
  const float inv = 1.0f / L;
  const long rowbase = ((long)b * 2048 + q_g) * 2048 + h * 64;
#pragma unroll
  for (int dn = 0; dn < 4; ++dn)
#pragma unroll
    for (int rp = 0; rp < 2; ++rp) {
      const unsigned pk = pack_bf16(accO[dn][2 * rp] * inv, accO[dn][2 * rp + 1] * inv);
      *(unsigned*)&O[rowbase + dn * 16 + l4 * 4 + 2 * rp] = pk;
    }
}

// ----------------------------------------------------------------
extern "C" void kernel_launch(void* const* d_in, const int* in_sizes, int n_in,
                              void* d_out, int out_size, void* d_ws, size_t ws_size,
                              hipStream_t stream) {
  const float* x   = (const float*)d_in[0];
  const float* wq  = (const float*)d_in[1];
  const float* wk  = (const float*)d_in[2];
  const float* wv  = (const float*)d_in[3];
  const float* wo  = (const float*)d_in[4];
  const float* qnw = (const float*)d_in[5];
  const float* knw = (const float*)d_in[6];
  float* out = (float*)d_out;

  char* ws = (char*)d_ws;
  size_t off = 0;
  auto carve = [&](size_t bytes) -> void* {
    void* p = ws + off;
    off += (bytes + 255) & ~(size_t)255;
    return p;
  };
  bf16* xb    = (bf16*)carve(8388608ull * 2);    // x bf16 [4096][2048]; reused as attn_out
  bf16* wqkvb = (bf16*)carve(6291456ull * 2);    // [3072][2048]
  bf16* wob   = (bf16*)carve(4194304ull * 2);    // [2048][2048]
  bf16* qkvb  = (bf16*)carve(12582912ull * 2);   // [4096][3072]
  bf16* Qh    = (bf16*)carve(8388608ull * 2);    // [2][32][2048][64]
  bf16* Kh    = (bf16*)carve(2097152ull * 2);    // [2][8][2048][64]
  bf16* Vt    = (bf16*)carve(2097152ull * 2);    // [2][8][64][2048]

  cvt_f32_to_bf16<<<4096, 256, 0, stream>>>(x, xb, 8388608L);
  cvt_f32_to_bf16<<<2048, 256, 0, stream>>>(wq, wqkvb, 4194304L);
  cvt_f32_to_bf16<<<512, 256, 0, stream>>>(wk, wqkvb + 4194304, 1048576L);
  cvt_f32_to_bf16<<<512, 256, 0, stream>>>(wv, wqkvb + 5242880, 1048576L);
  cvt_f32_to_bf16<<<2048, 256, 0, stream>>>(wo, wob, 4194304L);

  gemm_bt<bf16><<<dim3(24, 32), 256, 0, stream>>>(xb, wqkvb, qkvb, 4096, 3072, 2048);
  qk_norm_rope<<<40960, 256, 0, stream>>>(qkvb, qnw, knw, Qh, Kh);
  v_transpose<<<dim3(16, 32), 256, 0, stream>>>(qkvb, Vt);

  bf16* attnb = xb;   // xb is dead after the QKV GEMM
  attn_fwd<<<dim3(64, 32), 256, 0, stream>>>(Qh, Kh, Vt, attnb);

  gemm_bt<float><<<dim3(16, 32), 256, 0, stream>>>(attnb, wob, out, 4096, 2048, 2048);
}